// Round 10
// baseline (308.837 us; speedup 1.0000x reference)
//
#include <hip/hip_runtime.h>

// ElectrostaticEnergyLayer: per-pair shielded/switched Coulomb energy,
// scatter-added to atoms by idx_i.
//
// R18: 2-level binning to ELIMINATE the divergent-gather tax.
// Measured basis: ee_acc-style stream+LDS-bin runs at 5.2 TB/s (12us for
// 62MB + 16.7M LDS atomics); adding 16 Qa gathers/thread collapses to
// 1.45 TB/s (ee_radial, 116us) -- a ~100us scattered-access machine tax,
// insensitive to occupancy (R7), MLP batching (R9/R13/R17), cursors (R10),
// block count (R11). Fix: never gather Qa from L2.
//   P1 ee_binj: stream Dij/idx_i/idx_j (NO gathers), Rq=rn(R(d)*2^13),
//      bin (i:18|Rq:14)+(li_j) by j-bucket (128 buckets x 2048 atoms).
//   P2 ee_scat: per j-bucket chunk, load 8KB Qa slice to LDS; per entry:
//      Qj = LDS[li_j] (random in 2048 words ~ 2-way conflicts, free),
//      v = Qj*Rq*64 (2^19 scale), re-bin (li_i|v:21) by i-bucket with the
//      R15-proven staging machinery. Rq==0 entries (incl. list1 pads)
//      route to per-bank trash counters.
//   P3: existing ee_acc + ee_final.
// Workspace: split needs 148.9MB (l1a 58.7 + l1b 29.4 + list2 58.7 +
// part 2.1 + cursors); proven ws >= 96.2MB (R16 split ran). Tiered:
// split -> R15-exact fused (proven ~272us) -> fallbacks.
// Established: global atomics are memory-side on gfx950 (R12); rest
// ~120us is fixed harness overhead; bank/pad taxes latency-hidden.

#define KEHALF 7.199822675975274f
#define NB    128            // buckets (both i- and j-binning)
#define BSH   11             // atoms per bucket = 2048
#define BMASK 2047
#define CAP   114688         // entries per bucket region (both lists)
#define CURSTRIDE 16         // cursors 64 B apart
#define SCH   2              // phase-3 chunks per i-bucket
#define SCH1  16             // phase-2 chunks per j-bucket (2048 blocks)
#define SCAP  72             // LDS staging slots per bucket per block
#define SSTR  73             // stage stride (coprime with 32 banks)
#define VSCALE 524288.0f     // 2^19
#define VINV   (1.0f / 524288.0f)
#define RSCALE 8192.0f       // 2^13 (|R| <= 0.81 -> |Rq| <= 6636 < 2^13)
#define RINV   (1.0f / 8192.0f)
#define P1B   512            // phase-1 block threads
#define P1PAIRS 8192         // pairs per phase-1 block (512 thr x 16)

// radial factor R(d) via fast rcp/rsq: E = KEHALF * Qi * Qj * R(d)
__device__ __forceinline__ float radial_fast(float d) {
    float d2p1 = d * d + 1.0f;
    float rsq  = __builtin_amdgcn_rsqf(d2p1);          // 1/sqrt(d^2+1)
    float x    = 0.5f * d;
    float sw   = (x < 1.0f) ? 1.0f - x * x * x * (x * (6.0f * x - 15.0f) + 10.0f)
                            : 0.0f;
    float Eo = __builtin_amdgcn_rcpf(d) + d * 0.01f - 0.2f;
    float Es = rsq * (1.0f + 0.01f * d2p1) - 0.2f;     // 1/dsh + dsh/100
    return sw * Es + (1.0f - sw) * Eo;
}

// ---------------- P1: gather-free binning by j-bucket ---------------------
__global__ __launch_bounds__(P1B, 2) void ee_binj(
    const float* __restrict__ Dij,
    const float* __restrict__ Qa,       // spill path only
    const int*   __restrict__ idx_i,
    const int*   __restrict__ idx_j,
    unsigned int*   __restrict__ l1a,   // NB*CAP (i:18|Rq:14)
    unsigned short* __restrict__ l1b,   // NB*CAP li_j
    unsigned int*   __restrict__ cur1,
    float*          __restrict__ out)   // spill target (pre-zeroed)
{
    __shared__ unsigned int   sa[NB * SSTR];    // 37.4 KiB
    __shared__ unsigned short sb[NB * SSTR];    // 18.7 KiB
    __shared__ int lcur[NB + 32];
    __shared__ int gofs[NB];
    int tid = threadIdx.x;
    if (tid < NB + 32) lcur[tid] = 0;
    __syncthreads();

    long blockBase = (long)blockIdx.x * P1PAIRS;

    // phase A: 12 pure-stream loads, no gathers
    float4 d4[4]; int4 i4[4], j4[4];
#pragma unroll
    for (int g = 0; g < 4; ++g) {
        long o = blockBase + (long)(g * P1B + tid) * 4;
        d4[g] = *reinterpret_cast<const float4*>(Dij + o);
        i4[g] = *reinterpret_cast<const int4*>(idx_i + o);
        j4[g] = *reinterpret_cast<const int4*>(idx_j + o);
    }
    unsigned int   EA[16];
    unsigned short EB[16];
    int            BK[16];
    int trash = NB + (tid & 31);
#pragma unroll
    for (int g = 0; g < 4; ++g) {
        float dd[4] = {d4[g].x, d4[g].y, d4[g].z, d4[g].w};
        int   ii[4] = {i4[g].x, i4[g].y, i4[g].z, i4[g].w};
        int   jj[4] = {j4[g].x, j4[g].y, j4[g].z, j4[g].w};
#pragma unroll
        for (int k = 0; k < 4; ++k) {
            int m = g * 4 + k;
            int Rq = __float2int_rn(radial_fast(dd[k]) * RSCALE);
            EA[m] = ((unsigned int)ii[k] << 14) | ((unsigned int)Rq & 0x3FFFu);
            EB[m] = (unsigned short)(jj[k] & BMASK);
            BK[m] = (dd[k] <= 10.0f) ? (jj[k] >> BSH) : trash;
        }
    }

    // B1: unconditional ds_add_rtn (trash lanes spread per-bank)
    int SL[16];
#pragma unroll
    for (int m = 0; m < 16; ++m)
        SL[m] = atomicAdd(&lcur[BK[m]], 1);

    // B2: conditional ds_writes + ultra-rare exact spill
#pragma unroll
    for (int m = 0; m < 16; ++m) {
        if (BK[m] < NB) {
            if (SL[m] < SCAP) {
                sa[BK[m] * SSTR + SL[m]] = EA[m];
                sb[BK[m] * SSTR + SL[m]] = EB[m];
            } else {
                int atom = (int)(EA[m] >> 14);
                int jj   = (BK[m] << BSH) | (int)EB[m];
                int Rq   = ((int)(EA[m] << 18)) >> 18;
                atomicAdd(out + atom,
                          KEHALF * Qa[atom] * Qa[jj] * ((float)Rq * RINV));
            }
        }
    }
    __syncthreads();

    if (tid < NB) {
        int n = lcur[tid];
        if (n > SCAP) n = SCAP;
        lcur[tid] = n;
        int padded = (n + 3) & ~3;
        gofs[tid] = (int)atomicAdd(&cur1[tid * CURSTRIDE], (unsigned int)padded);
    }
    __syncthreads();

    int wave = tid >> 6, lane = tid & 63;
    for (int b = wave; b < NB; b += (P1B / 64)) {
        int n = lcur[b];
        int padded = (n + 3) & ~3;
        int go = gofs[b];
        long rb = (long)b * CAP;
        for (int i = lane; i < padded; i += 64) {
            bool real = (i < n);
            // pad: Rq = 0 -> routed to trash in P2, contributes nothing
            unsigned int   av = real ? sa[b * SSTR + i] : 0u;
            unsigned short bv = real ? sb[b * SSTR + i] : (unsigned short)0;
            int pos = go + i;
            if (pos < CAP) {
                l1a[rb + pos] = av;
                l1b[rb + pos] = bv;
            } else if (real) {
                int atom = (int)(av >> 14);
                int jj   = (b << BSH) | (int)bv;
                int Rq   = ((int)(av << 18)) >> 18;
                atomicAdd(out + atom,
                          KEHALF * Qa[atom] * Qa[jj] * ((float)Rq * RINV));
            }
        }
    }
}

// ---------------- P2: LDS-gather Qj, re-bin by i-bucket -------------------
__global__ __launch_bounds__(512) void ee_scat(
    const unsigned int*   __restrict__ l1a,
    const unsigned short* __restrict__ l1b,
    const unsigned int*   __restrict__ cur1,
    const float*          __restrict__ Qa,
    unsigned int* __restrict__ list2,   // NB*CAP (li_i:11|v:21)
    unsigned int* __restrict__ cur2,
    float*        __restrict__ out)
{
    __shared__ float qs[1 << BSH];              // 8 KiB j-bucket Qa slice
    __shared__ unsigned int stage[NB * SSTR];   // 37.4 KiB
    __shared__ int lcur[NB + 32];
    __shared__ int gofs[NB];
    int b = blockIdx.x >> 4;            // SCH1 == 16
    int s = blockIdx.x & 15;
    int t = threadIdx.x;
    if (t < NB + 32) lcur[t] = 0;
    reinterpret_cast<float4*>(qs)[t] =
        reinterpret_cast<const float4*>(Qa + ((long)b << BSH))[t];  // 512x16B
    __syncthreads();

    int n1 = (int)cur1[b * CURSTRIDE];
    if (n1 > CAP) n1 = CAP;
    int nq = n1 >> 2;
    int per = (nq + SCH1 - 1) >> 4;
    int q0 = s * per;
    int q1 = q0 + per; if (q1 > nq) q1 = nq;

    const uint4* a4  = reinterpret_cast<const uint4*>(l1a + (long)b * CAP);
    const uint2* b2p = reinterpret_cast<const uint2*>(l1b + (long)b * CAP);
    int trash = NB + (t & 31);
    for (int q = q0 + t; q < q1; q += 512) {
        uint4 ua = a4[q];
        uint2 ub = b2p[q];
        unsigned int us[4] = {ua.x, ua.y, ua.z, ua.w};
        int ls[4] = {(int)(ub.x & 0xFFFFu), (int)(ub.x >> 16),
                     (int)(ub.y & 0xFFFFu), (int)(ub.y >> 16)};
#pragma unroll
        for (int k = 0; k < 4; ++k) {
            unsigned int u = us[k];
            int Rq = ((int)(u << 18)) >> 18;
            int ii = (int)(u >> 14);
            float vf = qs[ls[k]] * (float)Rq;          // Qj * R * 2^13
            int v = __float2int_rn(vf * 64.0f);        // -> 2^19 scale
            int bk = (Rq != 0) ? (ii >> BSH) : trash;  // pads+R~0 -> trash
            int sl = atomicAdd(&lcur[bk], 1);
            if (bk < NB) {
                if (sl < SCAP) {
                    stage[bk * SSTR + sl] =
                        ((unsigned int)(ii & BMASK) << 21) |
                        ((unsigned int)v & 0x1FFFFFu);
                } else {
                    atomicAdd(out + ii, KEHALF * Qa[ii] * vf * RINV);
                }
            }
        }
    }
    __syncthreads();

    if (t < NB) {
        int n = lcur[t];
        if (n > SCAP) n = SCAP;
        lcur[t] = n;
        int padded = (n + 3) & ~3;
        gofs[t] = (int)atomicAdd(&cur2[t * CURSTRIDE], (unsigned int)padded);
    }
    __syncthreads();

    int wave = t >> 6, lane = t & 63;
    for (int bb = wave; bb < NB; bb += (512 / 64)) {
        int n = lcur[bb];
        int padded = (n + 3) & ~3;
        int go = gofs[bb];
        long rb = (long)bb * CAP;
        for (int i = lane; i < padded; i += 64) {
            unsigned int val = (i < n) ? stage[bb * SSTR + i]
                                       : ((unsigned int)(i & BMASK) << 21);
            int pos = go + i;
            if (pos < CAP) {
                list2[rb + pos] = val;
            } else if (i < n) {
                int atom = (bb << BSH) | (int)(val >> 21);
                int v    = ((int)(val << 11)) >> 11;
                atomicAdd(out + atom, KEHALF * Qa[atom] * ((float)v * VINV));
            }
        }
    }
}

// ---------------- R15-exact fused binning (middle tier) -------------------
__global__ __launch_bounds__(P1B, 4) void ee_bin(
    const float* __restrict__ Dij,
    const float* __restrict__ Qa,
    const int*   __restrict__ idx_i,
    const int*   __restrict__ idx_j,
    unsigned int* __restrict__ list,
    unsigned int* __restrict__ gcur,
    float*        __restrict__ out)
{
    __shared__ unsigned int stage[NB * SSTR];
    __shared__ int lcur[NB + 32];
    __shared__ int gofs[NB];
    int tid = threadIdx.x;
    if (tid < NB + 32) lcur[tid] = 0;
    __syncthreads();

    long blockBase = (long)blockIdx.x * P1PAIRS;

    unsigned int EN[16];
    int          BK[16];
    int trash = NB + (tid & 31);
#pragma unroll
    for (int g = 0; g < 4; ++g) {
        long o = blockBase + ((long)(g * P1B + tid)) * 4;
        int4 j4 = *reinterpret_cast<const int4*>(idx_j + o);
        float qj0 = Qa[j4.x], qj1 = Qa[j4.y], qj2 = Qa[j4.z], qj3 = Qa[j4.w];
        float4 d4 = *reinterpret_cast<const float4*>(Dij + o);
        int4   i4 = *reinterpret_cast<const int4*>(idx_i + o);
        float dd[4] = {d4.x, d4.y, d4.z, d4.w};
        float qq[4] = {qj0, qj1, qj2, qj3};
        int   ii[4] = {i4.x, i4.y, i4.z, i4.w};
#pragma unroll
        for (int k = 0; k < 4; ++k) {
            int m = g * 4 + k;
            float d = dd[k];
            float w = qq[k] * radial_fast(d);
            int v = __float2int_rn(w * VSCALE);
            EN[m] = ((unsigned int)(ii[k] & BMASK) << 21) |
                    ((unsigned int)v & 0x1FFFFFu);
            BK[m] = (d <= 10.0f) ? (ii[k] >> BSH) : trash;
        }
    }

    int SL[16];
#pragma unroll
    for (int m = 0; m < 16; ++m)
        SL[m] = atomicAdd(&lcur[BK[m]], 1);

#pragma unroll
    for (int m = 0; m < 16; ++m) {
        if (BK[m] < NB) {
            if (SL[m] < SCAP) {
                stage[BK[m] * SSTR + SL[m]] = EN[m];
            } else {
                int atom = (BK[m] << BSH) | (int)(EN[m] >> 21);
                int v    = ((int)(EN[m] << 11)) >> 11;
                atomicAdd(out + atom, KEHALF * Qa[atom] * ((float)v * VINV));
            }
        }
    }
    __syncthreads();

    if (tid < NB) {
        int n = lcur[tid];
        if (n > SCAP) n = SCAP;
        lcur[tid] = n;
        int padded = (n + 3) & ~3;
        gofs[tid] = (int)atomicAdd(&gcur[tid * CURSTRIDE], (unsigned int)padded);
    }
    __syncthreads();

    int wave = tid >> 6, lane = tid & 63;
    for (int b = wave; b < NB; b += (P1B / 64)) {
        int n = lcur[b];
        int padded = (n + 3) & ~3;
        int go = gofs[b];
        long rb = (long)b * CAP;
        for (int i = lane; i < padded; i += 64) {
            unsigned int val = (i < n) ? stage[b * SSTR + i]
                                       : ((unsigned int)(i & BMASK) << 21);
            int pos = go + i;
            if (pos < CAP)
                list[rb + pos] = val;
        }
    }
}

// ---------------- P3: per-bucket-chunk LDS int accumulation ---------------
__global__ __launch_bounds__(512) void ee_acc(
    const unsigned int* __restrict__ list,
    const unsigned int* __restrict__ gcur,
    int* __restrict__ partials)          // [NB*SCH][2048]
{
    __shared__ int acc[1 << BSH];
    int b = blockIdx.x / SCH;
    int s = blockIdx.x % SCH;
    int t = threadIdx.x;
#pragma unroll
    for (int r = 0; r < (1 << BSH) / 512; ++r) acc[t + r * 512] = 0;
    __syncthreads();

    int n = (int)gcur[b * CURSTRIDE];
    if (n > CAP) n = CAP;
    int nq = n >> 2;
    int per = (nq + SCH - 1) / SCH;
    int q0 = s * per;
    int q1 = q0 + per; if (q1 > nq) q1 = nq;

    const uint4* lp4 = reinterpret_cast<const uint4*>(list + (long)b * CAP);
    for (int q = q0 + t; q < q1; q += 512) {
        uint4 u4 = lp4[q];
        unsigned int us[4] = {u4.x, u4.y, u4.z, u4.w};
#pragma unroll
        for (int k = 0; k < 4; ++k) {
            unsigned int u = us[k];
            int li = (int)(u >> 21);
            int v  = ((int)(u << 11)) >> 11;
            atomicAdd(&acc[li], v);
        }
    }
    __syncthreads();

    int* pp = partials + ((long)b * SCH + s) * (1 << BSH);
#pragma unroll
    for (int r = 0; r < (1 << BSH) / 512; ++r) pp[t + r * 512] = acc[t + r * 512];
}

// ---------------- Final: combine partials, apply KEHALF*Qi, add spill -----
__global__ __launch_bounds__(256) void ee_final(
    const int* __restrict__ partials,
    const float* __restrict__ Qa,
    float* __restrict__ out, int nAtoms)
{
    int q = blockIdx.x * blockDim.x + threadIdx.x;
    int n4 = nAtoms >> 2;
    if (q >= n4) return;
    int a0 = q << 2;
    int b  = a0 >> BSH;
    int li = a0 & BMASK;
    long base = (long)(b * SCH) * (1 << BSH) + li;
    int4 s = {0, 0, 0, 0};
#pragma unroll
    for (int r = 0; r < SCH; ++r) {
        int4 p = *reinterpret_cast<const int4*>(partials + base + (long)r * (1 << BSH));
        s.x += p.x; s.y += p.y; s.z += p.z; s.w += p.w;
    }
    float4 qv = reinterpret_cast<const float4*>(Qa)[q];
    float4 sp = reinterpret_cast<const float4*>(out)[q];
    float4 o;
    o.x = KEHALF * qv.x * ((float)s.x * VINV) + sp.x;
    o.y = KEHALF * qv.y * ((float)s.y * VINV) + sp.y;
    o.z = KEHALF * qv.z * ((float)s.z * VINV) + sp.z;
    o.w = KEHALF * qv.w * ((float)s.w * VINV) + sp.w;
    reinterpret_cast<float4*>(out)[q] = o;
}

// ---------------- Fallbacks ----------------------------------------------
#define FP_SCALE 4194304.0f
#define FP_INV   (1.0f / 4194304.0f)

__device__ __forceinline__ float radial_exact(float d) {
    float dsh = sqrtf(d * d + 1.0f);
    float x   = 0.5f * d;
    float sw  = (x < 1.0f) ? 1.0f - x * x * x * (x * (6.0f * x - 15.0f) + 10.0f)
                           : 0.0f;
    float Eo = 1.0f / d   + d   * 0.01f - 0.2f;
    float Es = 1.0f / dsh + dsh * 0.01f - 0.2f;
    return sw * Es + (1.0f - sw) * Eo;
}

__global__ __launch_bounds__(256) void ee_pair_fix(
    const float* __restrict__ Dij,
    const float* __restrict__ Qa,
    const int*   __restrict__ idx_i,
    const int*   __restrict__ idx_j,
    int*         __restrict__ acc,
    int P)
{
    long base = ((long)blockIdx.x * blockDim.x + threadIdx.x) * 4;
    if (base >= P) return;
    float4 d4 = *reinterpret_cast<const float4*>(Dij + base);
    int4   i4 = *reinterpret_cast<const int4*>(idx_i + base);
    int4   j4 = *reinterpret_cast<const int4*>(idx_j + base);
    float D[4]  = {d4.x, d4.y, d4.z, d4.w};
    int   ii[4] = {i4.x, i4.y, i4.z, i4.w};
    int   jj[4] = {j4.x, j4.y, j4.z, j4.w};
#pragma unroll
    for (int k = 0; k < 4; ++k) {
        float d = D[k];
        if (d > 10.0f) continue;
        float e = KEHALF * Qa[ii[k]] * Qa[jj[k]] * radial_exact(d);
        atomicAdd(acc + ii[k], __float2int_rn(e * FP_SCALE));
    }
}

__global__ __launch_bounds__(256) void ee_convert(
    const int* __restrict__ acc, float* __restrict__ out, int nAtoms)
{
    int n4 = nAtoms >> 2;
    int q = blockIdx.x * blockDim.x + threadIdx.x;
    if (q >= n4) return;
    int4 a = reinterpret_cast<const int4*>(acc)[q];
    float4 o;
    o.x = (float)a.x * FP_INV;
    o.y = (float)a.y * FP_INV;
    o.z = (float)a.z * FP_INV;
    o.w = (float)a.w * FP_INV;
    reinterpret_cast<float4*>(out)[q] = o;
}

__global__ __launch_bounds__(256) void ee_pair_direct(
    const float* __restrict__ Dij,
    const float* __restrict__ Qa,
    const int*   __restrict__ idx_i,
    const int*   __restrict__ idx_j,
    float*       __restrict__ out,
    int P)
{
    long t = (long)blockIdx.x * blockDim.x + threadIdx.x;
    if (t >= P) return;
    float d = Dij[t];
    if (d > 10.0f) return;
    atomicAdd(out + idx_i[t], KEHALF * Qa[idx_i[t]] * Qa[idx_j[t]] * radial_exact(d));
}

extern "C" void kernel_launch(void* const* d_in, const int* in_sizes, int n_in,
                              void* d_out, int out_size, void* d_ws, size_t ws_size,
                              hipStream_t stream) {
    const float* Dij   = (const float*)d_in[0];
    const float* Qa    = (const float*)d_in[1];
    const int*   idx_i = (const int*)d_in[2];
    const int*   idx_j = (const int*)d_in[3];
    float*       out   = (float*)d_out;

    int P      = in_sizes[0];
    int nAtoms = in_sizes[1];

    size_t lA    = (size_t)NB * CAP * sizeof(unsigned int);    // 58.7 MB
    size_t lB    = (size_t)NB * CAP * sizeof(unsigned short);  // 29.4 MB
    size_t l2    = (size_t)NB * CAP * sizeof(unsigned int);    // 58.7 MB
    size_t partB = (size_t)NB * SCH * (1 << BSH) * sizeof(int);// 2.1 MB
    size_t curB  = (size_t)NB * CURSTRIDE * sizeof(unsigned int); // 8 KB
    size_t splitTotal = lA + lB + l2 + partB + 2 * curB;       // 148.9 MB

    if (ws_size >= splitTotal && nAtoms == NB * (1 << BSH) &&
        (P % P1PAIRS) == 0) {
        // ---- R18 split (2-level binning, gather-free) ----
        unsigned int*   l1a  = (unsigned int*)d_ws;
        unsigned short* l1b  = (unsigned short*)((char*)d_ws + lA);
        unsigned int*   lst2 = (unsigned int*)((char*)d_ws + lA + lB);
        int*            part = (int*)((char*)d_ws + lA + lB + l2);
        unsigned int*   cur1 = (unsigned int*)((char*)d_ws + lA + lB + l2 + partB);
        unsigned int*   cur2 = (unsigned int*)((char*)d_ws + lA + lB + l2 + partB + curB);
        hipMemsetAsync(cur1, 0, 2 * curB, stream);             // cur1 + cur2
        hipMemsetAsync(out, 0, (size_t)out_size * sizeof(float), stream);
        ee_binj<<<P / P1PAIRS, P1B, 0, stream>>>(Dij, Qa, idx_i, idx_j,
                                                 l1a, l1b, cur1, out);
        ee_scat<<<NB * SCH1, 512, 0, stream>>>(l1a, l1b, cur1, Qa,
                                               lst2, cur2, out);
        ee_acc<<<NB * SCH, 512, 0, stream>>>(lst2, cur2, part);
        ee_final<<<(nAtoms / 4 + 255) / 256, 256, 0, stream>>>(part, Qa, out,
                                                               nAtoms);
    } else if (ws_size >= lA + partB + curB &&
               nAtoms == NB * (1 << BSH) && (P % P1PAIRS) == 0) {
        // ---- R15-exact fused pipeline (proven ~272us) ----
        unsigned int* list = (unsigned int*)d_ws;
        int*          part = (int*)((char*)d_ws + lA);
        unsigned int* gcur = (unsigned int*)((char*)d_ws + lA + partB);
        hipMemsetAsync(gcur, 0, curB, stream);
        hipMemsetAsync(out, 0, (size_t)out_size * sizeof(float), stream);
        ee_bin<<<P / P1PAIRS, P1B, 0, stream>>>(Dij, Qa, idx_i, idx_j,
                                                list, gcur, out);
        ee_acc<<<NB * SCH, 512, 0, stream>>>(list, gcur, part);
        ee_final<<<(nAtoms / 4 + 255) / 256, 256, 0, stream>>>(part, Qa, out,
                                                               nAtoms);
    } else if (ws_size >= (size_t)nAtoms * sizeof(int) &&
               (nAtoms & 3) == 0 && (P & 3) == 0) {
        int* acc = (int*)d_ws;
        hipMemsetAsync(acc, 0, (size_t)nAtoms * sizeof(int), stream);
        int grid = (P / 4 + 255) / 256;
        ee_pair_fix<<<grid, 256, 0, stream>>>(Dij, Qa, idx_i, idx_j, acc, P);
        ee_convert<<<(nAtoms / 4 + 255) / 256, 256, 0, stream>>>(acc, out, nAtoms);
    } else {
        hipMemsetAsync(out, 0, (size_t)out_size * sizeof(float), stream);
        int grid = (P + 255) / 256;
        ee_pair_direct<<<grid, 256, 0, stream>>>(Dij, Qa, idx_i, idx_j, out, P);
    }
}

// Round 11
// 302.724 us; speedup vs baseline: 1.0202x; 1.0202x over previous
//
#include <hip/hip_runtime.h>

// ElectrostaticEnergyLayer: per-pair shielded/switched Coulomb energy,
// scatter-added to atoms by idx_i.
//
// R19: phase-overlap via block co-residency. Ablation matrix (R16/R18):
// gather-only 116us, stage-only 112us, fused 134us -- no single ingredient
// dominates and no pipe exceeds 25%. Shared structure: barrier-separated
// {stream -> LDS -> copy-out} phases with only ~2 resident 512-thr blocks
// per CU (38-55% occ, 38-57KB LDS) => memory pipe idles during LDS phases
// and vice versa (~40% duty cycle = the measured 1.2-1.8 TB/s). R11 showed
// the inverse (bigger LDS, fewer blocks) regresses +23us. Fix: halve the
// block -- 256 thr / 4096 pairs / SCAP 48 / stride 49 => 26.2 KB LDS =>
// ~6 blocks/CU, so different blocks' phases interleave on each CU.
// Stats: lambda=26.4/bucket, SCAP 48 = +4.2 sigma (~6 exact-float spills
// per launch); CAP slack 35 sigma; workspace identical to proven footprint.
// Established: global atomics are memory-side on gfx950 (R12, 432MB
// WRITE_SIZE) => binned-LDS pipeline mandatory; rest ~120us is fixed
// harness overhead (R12 3-dispatch control); exec-masked B1 costs +12us
// (R14) => keep unconditional B1 with per-bank trash counters (R15).
// Fast math: v_rcp/v_rsq builtins; Es = rsq*(1+0.01*(d^2+1))-0.2 (rel err
// ~1e-5 vs 0.33 abs threshold).

#define KEHALF 7.199822675975274f
#define NB    128            // buckets
#define BSH   11             // atoms per bucket = 2048
#define BMASK 2047
#define CAP   126976         // entries per bucket region (list = 62 MiB)
#define CURSTRIDE 16         // cursors 64 B apart
#define SCH   2              // phase-2 chunks per bucket
#define SCAP  48             // LDS staging slots per bucket per block
#define SSTR  49             // stage stride (coprime with 32 banks)
#define VSCALE 524288.0f     // 2^19; |Qj*R| <= ~1.6 -> |v| < 2^20
#define VINV   (1.0f / 524288.0f)
#define P1B   256            // phase-1 block threads (halved for residency)
#define P1PAIRS 4096         // pairs per phase-1 block (256 thr x 16)

// radial factor R(d) via fast rcp/rsq: E = KEHALF * Qi * Qj * R(d)
__device__ __forceinline__ float radial_fast(float d) {
    float d2p1 = d * d + 1.0f;
    float rsq  = __builtin_amdgcn_rsqf(d2p1);          // 1/sqrt(d^2+1)
    float x    = 0.5f * d;
    float sw   = (x < 1.0f) ? 1.0f - x * x * x * (x * (6.0f * x - 15.0f) + 10.0f)
                            : 0.0f;
    float Eo = __builtin_amdgcn_rcpf(d) + d * 0.01f - 0.2f;
    float Es = rsq * (1.0f + 0.01f * d2p1) - 0.2f;     // 1/dsh + dsh/100
    return sw * Es + (1.0f - sw) * Eo;
}

// ---------------- Phase 1: LDS-staged binning, 6 blocks/CU ----------------
__global__ __launch_bounds__(P1B, 6) void ee_bin(
    const float* __restrict__ Dij,
    const float* __restrict__ Qa,
    const int*   __restrict__ idx_i,
    const int*   __restrict__ idx_j,
    unsigned int* __restrict__ list,    // NB * CAP packed entries
    unsigned int* __restrict__ gcur,    // NB cursors, stride CURSTRIDE
    float*        __restrict__ out)     // spill target (pre-zeroed)
{
    __shared__ unsigned int stage[NB * SSTR];   // 25.1 KiB
    __shared__ int lcur[NB + 32];               // +32 per-bank trash counters
    __shared__ int gofs[NB];
    int tid = threadIdx.x;
    if (tid < NB + 32) lcur[tid] = 0;
    __syncthreads();

    long blockBase = (long)blockIdx.x * P1PAIRS;

    // ---- phase A: compute (R13/R15-proven interleave); no LDS ops ----
    unsigned int EN[16];   // (li << 21) | (v & 0x1FFFFF)
    int          BK[16];   // bucket, or NB+(tid&31) trash slot if d > 10
    int trash = NB + (tid & 31);
#pragma unroll
    for (int g = 0; g < 4; ++g) {
        long o = blockBase + ((long)(g * P1B + tid)) * 4;
        int4 j4 = *reinterpret_cast<const int4*>(idx_j + o);
        float qj0 = Qa[j4.x], qj1 = Qa[j4.y], qj2 = Qa[j4.z], qj3 = Qa[j4.w];
        float4 d4 = *reinterpret_cast<const float4*>(Dij + o);
        int4   i4 = *reinterpret_cast<const int4*>(idx_i + o);
        float dd[4] = {d4.x, d4.y, d4.z, d4.w};
        float qq[4] = {qj0, qj1, qj2, qj3};
        int   ii[4] = {i4.x, i4.y, i4.z, i4.w};
#pragma unroll
        for (int k = 0; k < 4; ++k) {
            int m = g * 4 + k;
            float d = dd[k];
            float w = qq[k] * radial_fast(d);               // deferred Qi
            int v = __float2int_rn(w * VSCALE);
            EN[m] = ((unsigned int)(ii[k] & BMASK) << 21) |
                    ((unsigned int)v & 0x1FFFFFu);
            BK[m] = (d <= 10.0f) ? (ii[k] >> BSH) : trash;  // cndmask, no branch
        }
    }

    // ---- phase B1: 16 unconditional ds_add_rtn, back-to-back ----
    int SL[16];
#pragma unroll
    for (int m = 0; m < 16; ++m)
        SL[m] = atomicAdd(&lcur[BK[m]], 1);

    // ---- phase B2: conditional ds_writes + rare decode-spill ----
#pragma unroll
    for (int m = 0; m < 16; ++m) {
        if (BK[m] < NB) {
            if (SL[m] < SCAP) {
                stage[BK[m] * SSTR + SL[m]] = EN[m];
            } else {
                // ~6 events/launch at SCAP=48 (+4.2 sigma): exact spill
                int atom = (BK[m] << BSH) | (int)(EN[m] >> 21);
                int v    = ((int)(EN[m] << 11)) >> 11;
                atomicAdd(out + atom, KEHALF * Qa[atom] * ((float)v * VINV));
            }
        }
    }
    __syncthreads();

    // one padded (4-entry = 16 B multiple) reservation per (block, bucket)
    if (tid < NB) {
        int n = lcur[tid];
        if (n > SCAP) n = SCAP;
        lcur[tid] = n;                          // clamp for copy-out
        int padded = (n + 3) & ~3;
        gofs[tid] = (int)atomicAdd(&gcur[tid * CURSTRIDE], (unsigned int)padded);
    }
    __syncthreads();

    // coalesced copy-out: wave w handles buckets w, w+4, ... (4 waves)
    int wave = tid >> 6, lane = tid & 63;
    for (int b = wave; b < NB; b += (P1B / 64)) {
        int n = lcur[b];
        int padded = (n + 3) & ~3;              // <= 48 < 64: single pass
        int go = gofs[b];
        long rb = (long)b * CAP;
        for (int i = lane; i < padded; i += 64) {
            // pad entries: v=0, li spread (no acc[0] hammering in phase 2)
            unsigned int val = (i < n) ? stage[b * SSTR + i]
                                       : ((unsigned int)(i & BMASK) << 21);
            int pos = go + i;
            if (pos < CAP)                       // statistical hard guard
                list[rb + pos] = val;
        }
    }
}

// ---------------- Phase 2: per-bucket-chunk LDS int accumulation ----------
__global__ __launch_bounds__(512) void ee_acc(
    const unsigned int* __restrict__ list,
    const unsigned int* __restrict__ gcur,
    int* __restrict__ partials)          // [NB*SCH][2048]
{
    __shared__ int acc[1 << BSH];
    int b = blockIdx.x / SCH;
    int s = blockIdx.x % SCH;
    int t = threadIdx.x;
#pragma unroll
    for (int r = 0; r < (1 << BSH) / 512; ++r) acc[t + r * 512] = 0;
    __syncthreads();

    int n = (int)gcur[b * CURSTRIDE];    // padded total, multiple of 4
    if (n > CAP) n = CAP;
    int nq = n >> 2;                     // uint4 count
    int per = (nq + SCH - 1) / SCH;
    int q0 = s * per;
    int q1 = q0 + per; if (q1 > nq) q1 = nq;

    const uint4* lp4 = reinterpret_cast<const uint4*>(list + (long)b * CAP);
    for (int q = q0 + t; q < q1; q += 512) {
        uint4 u4 = lp4[q];
        unsigned int us[4] = {u4.x, u4.y, u4.z, u4.w};
#pragma unroll
        for (int k = 0; k < 4; ++k) {
            unsigned int u = us[k];
            int li = (int)(u >> 21);
            int v  = ((int)(u << 11)) >> 11;   // sign-extend 21-bit payload
            atomicAdd(&acc[li], v);            // native ds_add_u32
        }
    }
    __syncthreads();

    int* pp = partials + ((long)b * SCH + s) * (1 << BSH);
#pragma unroll
    for (int r = 0; r < (1 << BSH) / 512; ++r) pp[t + r * 512] = acc[t + r * 512];
}

// ---------------- Phase 3: combine partials, apply KEHALF*Qi, add spill ----
__global__ __launch_bounds__(256) void ee_final(
    const int* __restrict__ partials,
    const float* __restrict__ Qa,
    float* __restrict__ out, int nAtoms)
{
    int q = blockIdx.x * blockDim.x + threadIdx.x;      // one int4 per thread
    int n4 = nAtoms >> 2;
    if (q >= n4) return;
    int a0 = q << 2;
    int b  = a0 >> BSH;
    int li = a0 & BMASK;
    long base = (long)(b * SCH) * (1 << BSH) + li;
    int4 s = {0, 0, 0, 0};
#pragma unroll
    for (int r = 0; r < SCH; ++r) {
        int4 p = *reinterpret_cast<const int4*>(partials + base + (long)r * (1 << BSH));
        s.x += p.x; s.y += p.y; s.z += p.z; s.w += p.w;
    }
    float4 qv = reinterpret_cast<const float4*>(Qa)[q];
    float4 sp = reinterpret_cast<const float4*>(out)[q];   // spill (or 0)
    float4 o;
    o.x = KEHALF * qv.x * ((float)s.x * VINV) + sp.x;
    o.y = KEHALF * qv.y * ((float)s.y * VINV) + sp.y;
    o.z = KEHALF * qv.z * ((float)s.z * VINV) + sp.z;
    o.w = KEHALF * qv.w * ((float)s.w * VINV) + sp.w;
    reinterpret_cast<float4*>(out)[q] = o;
}

// ---------------- Fallback: int fixed-point global atomics (R3) --------
#define FP_SCALE 4194304.0f
#define FP_INV   (1.0f / 4194304.0f)

__device__ __forceinline__ float radial_exact(float d) {
    float dsh = sqrtf(d * d + 1.0f);
    float x   = 0.5f * d;
    float sw  = (x < 1.0f) ? 1.0f - x * x * x * (x * (6.0f * x - 15.0f) + 10.0f)
                           : 0.0f;
    float Eo = 1.0f / d   + d   * 0.01f - 0.2f;
    float Es = 1.0f / dsh + dsh * 0.01f - 0.2f;
    return sw * Es + (1.0f - sw) * Eo;
}

__global__ __launch_bounds__(256) void ee_pair_fix(
    const float* __restrict__ Dij,
    const float* __restrict__ Qa,
    const int*   __restrict__ idx_i,
    const int*   __restrict__ idx_j,
    int*         __restrict__ acc,
    int P)
{
    long base = ((long)blockIdx.x * blockDim.x + threadIdx.x) * 4;
    if (base >= P) return;
    float4 d4 = *reinterpret_cast<const float4*>(Dij + base);
    int4   i4 = *reinterpret_cast<const int4*>(idx_i + base);
    int4   j4 = *reinterpret_cast<const int4*>(idx_j + base);
    float D[4]  = {d4.x, d4.y, d4.z, d4.w};
    int   ii[4] = {i4.x, i4.y, i4.z, i4.w};
    int   jj[4] = {j4.x, j4.y, j4.z, j4.w};
#pragma unroll
    for (int k = 0; k < 4; ++k) {
        float d = D[k];
        if (d > 10.0f) continue;
        float e = KEHALF * Qa[ii[k]] * Qa[jj[k]] * radial_exact(d);
        atomicAdd(acc + ii[k], __float2int_rn(e * FP_SCALE));
    }
}

__global__ __launch_bounds__(256) void ee_convert(
    const int* __restrict__ acc, float* __restrict__ out, int nAtoms)
{
    int n4 = nAtoms >> 2;
    int q = blockIdx.x * blockDim.x + threadIdx.x;
    if (q >= n4) return;
    int4 a = reinterpret_cast<const int4*>(acc)[q];
    float4 o;
    o.x = (float)a.x * FP_INV;
    o.y = (float)a.y * FP_INV;
    o.z = (float)a.z * FP_INV;
    o.w = (float)a.w * FP_INV;
    reinterpret_cast<float4*>(out)[q] = o;
}

__global__ __launch_bounds__(256) void ee_pair_direct(
    const float* __restrict__ Dij,
    const float* __restrict__ Qa,
    const int*   __restrict__ idx_i,
    const int*   __restrict__ idx_j,
    float*       __restrict__ out,
    int P)
{
    long t = (long)blockIdx.x * blockDim.x + threadIdx.x;
    if (t >= P) return;
    float d = Dij[t];
    if (d > 10.0f) return;
    atomicAdd(out + idx_i[t], KEHALF * Qa[idx_i[t]] * Qa[idx_j[t]] * radial_exact(d));
}

extern "C" void kernel_launch(void* const* d_in, const int* in_sizes, int n_in,
                              void* d_out, int out_size, void* d_ws, size_t ws_size,
                              hipStream_t stream) {
    const float* Dij   = (const float*)d_in[0];
    const float* Qa    = (const float*)d_in[1];
    const int*   idx_i = (const int*)d_in[2];
    const int*   idx_j = (const int*)d_in[3];
    float*       out   = (float*)d_out;

    int P      = in_sizes[0];
    int nAtoms = in_sizes[1];

    size_t listBytes = (size_t)NB * CAP * sizeof(unsigned int);          // 62 MiB
    size_t partBytes = (size_t)NB * SCH * (1 << BSH) * sizeof(int);      // 2 MiB
    size_t curBytes  = (size_t)NB * CURSTRIDE * sizeof(unsigned int);    // 8 KiB

    if (ws_size >= listBytes + partBytes + curBytes &&
        nAtoms == NB * (1 << BSH) && (P % P1PAIRS) == 0) {
        unsigned int* list = (unsigned int*)d_ws;
        int*          part = (int*)((char*)d_ws + listBytes);
        unsigned int* gcur = (unsigned int*)((char*)d_ws + listBytes + partBytes);
        hipMemsetAsync(gcur, 0, curBytes, stream);
        hipMemsetAsync(out, 0, (size_t)out_size * sizeof(float), stream); // spill base
        int grid1 = P / P1PAIRS;                                          // 4096
        ee_bin<<<grid1, P1B, 0, stream>>>(Dij, Qa, idx_i, idx_j, list, gcur, out);
        ee_acc<<<NB * SCH, 512, 0, stream>>>(list, gcur, part);
        ee_final<<<(nAtoms / 4 + 255) / 256, 256, 0, stream>>>(part, Qa, out, nAtoms);
    } else if (ws_size >= (size_t)nAtoms * sizeof(int) &&
               (nAtoms & 3) == 0 && (P & 3) == 0) {
        int* acc = (int*)d_ws;
        hipMemsetAsync(acc, 0, (size_t)nAtoms * sizeof(int), stream);
        int grid = (P / 4 + 255) / 256;
        ee_pair_fix<<<grid, 256, 0, stream>>>(Dij, Qa, idx_i, idx_j, acc, P);
        ee_convert<<<(nAtoms / 4 + 255) / 256, 256, 0, stream>>>(acc, out, nAtoms);
    } else {
        hipMemsetAsync(out, 0, (size_t)out_size * sizeof(float), stream);
        int grid = (P + 255) / 256;
        ee_pair_direct<<<grid, 256, 0, stream>>>(Dij, Qa, idx_i, idx_j, out, P);
    }
}

// Round 12
// 272.773 us; speedup vs baseline: 1.1322x; 1.1098x over previous
//
#include <hip/hip_runtime.h>

// ElectrostaticEnergyLayer: per-pair shielded/switched Coulomb energy,
// scatter-added to atoms by idx_i.
//
// R20: TERMINAL REVERT to the best measured configuration (R15: 272.8us
// total, ee_bin 134.3us; statistically equal to session-best R17 271.0).
// The structural map is complete -- every axis tried:
//   occupancy (R7/R19 null/-30), gather-MLP x3 (R9/R13/R17: compiler
//   re-serializes, VGPR pinned <=48), phase-split (R13: -9, the only win),
//   exec-masked B1 (R14: +12), bank/pad/trash taxes (R14/R15: hidden),
//   global atomics (R12: memory-side RMW, 4x worse), cursor contention
//   (R10: null), block size half/double (R19 +30 / R11 +23 => 512thr/8192
//   is the U-curve minimum), fission (R16: +40), 2-level gather-free
//   binning (R18: +37).
// Ablation: gather-only 116us, stage-only 112us, fused 134us -- the fused
// kernel already overlaps 94us of its halves; no pipe exceeds 25% because
// the bound is interleaved gather/LDS latency structure, not bandwidth.
// "Rest" ~115-120us is fixed harness overhead (R12 3-dispatch control).
// Practical floor ~271-273us.
// Fast math: v_rcp/v_rsq builtins; Es = rsq*(1+0.01*(d^2+1))-0.2 (no sqrt,
// no div; rel err ~1e-5 vs 0.33 abs threshold).

#define KEHALF 7.199822675975274f
#define NB    128            // buckets
#define BSH   11             // atoms per bucket = 2048
#define BMASK 2047
#define CAP   126976         // entries per bucket region (list = 62 MiB)
#define CURSTRIDE 16         // cursors 64 B apart
#define SCH   2              // phase-2 chunks per bucket
#define SCAP  72             // LDS staging slots per bucket per block
#define SSTR  73             // stage stride (coprime with 32 banks)
#define VSCALE 524288.0f     // 2^19; |Qj*R| <= ~1.6 -> |v| < 2^20
#define VINV   (1.0f / 524288.0f)
#define P1B   512            // phase-1 block threads
#define P1PAIRS 8192         // pairs per phase-1 block (512 thr x 16)

// radial factor R(d) via fast rcp/rsq: E = KEHALF * Qi * Qj * R(d)
__device__ __forceinline__ float radial_fast(float d) {
    float d2p1 = d * d + 1.0f;
    float rsq  = __builtin_amdgcn_rsqf(d2p1);          // 1/sqrt(d^2+1)
    float x    = 0.5f * d;
    float sw   = (x < 1.0f) ? 1.0f - x * x * x * (x * (6.0f * x - 15.0f) + 10.0f)
                            : 0.0f;
    float Eo = __builtin_amdgcn_rcpf(d) + d * 0.01f - 0.2f;
    float Es = rsq * (1.0f + 0.01f * d2p1) - 0.2f;     // 1/dsh + dsh/100
    return sw * Es + (1.0f - sw) * Eo;
}

// ---------------- Phase 1: LDS-staged binning, split compute/staging ------
__global__ __launch_bounds__(P1B, 4) void ee_bin(
    const float* __restrict__ Dij,
    const float* __restrict__ Qa,
    const int*   __restrict__ idx_i,
    const int*   __restrict__ idx_j,
    unsigned int* __restrict__ list,    // NB * CAP packed entries
    unsigned int* __restrict__ gcur,    // NB cursors, stride CURSTRIDE
    float*        __restrict__ out)     // spill target (pre-zeroed)
{
    __shared__ unsigned int stage[NB * SSTR];   // 36.5 KiB
    __shared__ int lcur[NB + 32];               // +32 per-bank trash counters
    __shared__ int gofs[NB];
    int tid = threadIdx.x;
    if (tid < NB + 32) lcur[tid] = 0;
    __syncthreads();

    long blockBase = (long)blockIdx.x * P1PAIRS;

    // ---- phase A: compute. R8-exact load/gather interleave; no LDS ops ----
    unsigned int EN[16];   // (li << 21) | (v & 0x1FFFFF)
    int          BK[16];   // bucket, or NB+(tid&31) trash slot if d > 10
    int trash = NB + (tid & 31);
#pragma unroll
    for (int g = 0; g < 4; ++g) {
        long o = blockBase + ((long)(g * P1B + tid)) * 4;
        int4 j4 = *reinterpret_cast<const int4*>(idx_j + o);
        float qj0 = Qa[j4.x], qj1 = Qa[j4.y], qj2 = Qa[j4.z], qj3 = Qa[j4.w];
        float4 d4 = *reinterpret_cast<const float4*>(Dij + o);
        int4   i4 = *reinterpret_cast<const int4*>(idx_i + o);
        float dd[4] = {d4.x, d4.y, d4.z, d4.w};
        float qq[4] = {qj0, qj1, qj2, qj3};
        int   ii[4] = {i4.x, i4.y, i4.z, i4.w};
#pragma unroll
        for (int k = 0; k < 4; ++k) {
            int m = g * 4 + k;
            float d = dd[k];
            float w = qq[k] * radial_fast(d);               // deferred Qi
            int v = __float2int_rn(w * VSCALE);
            EN[m] = ((unsigned int)(ii[k] & BMASK) << 21) |
                    ((unsigned int)v & 0x1FFFFFu);
            BK[m] = (d <= 10.0f) ? (ii[k] >> BSH) : trash;  // cndmask, no branch
        }
    }

    // ---- phase B1: 16 unconditional ds_add_rtn, back-to-back ----
    int SL[16];
#pragma unroll
    for (int m = 0; m < 16; ++m)
        SL[m] = atomicAdd(&lcur[BK[m]], 1);

    // ---- phase B2: conditional ds_writes + rare decode-spill ----
#pragma unroll
    for (int m = 0; m < 16; ++m) {
        if (BK[m] < NB) {
            if (SL[m] < SCAP) {
                stage[BK[m] * SSTR + SL[m]] = EN[m];
            } else {
                // rare (~900/launch at SCAP=72): quantized spill, no re-gather
                int atom = (BK[m] << BSH) | (int)(EN[m] >> 21);
                int v    = ((int)(EN[m] << 11)) >> 11;
                atomicAdd(out + atom, KEHALF * Qa[atom] * ((float)v * VINV));
            }
        }
    }
    __syncthreads();

    // one padded (4-entry = 16 B multiple) reservation per (block, bucket)
    if (tid < NB) {
        int n = lcur[tid];
        if (n > SCAP) n = SCAP;
        lcur[tid] = n;                          // clamp for copy-out
        int padded = (n + 3) & ~3;
        gofs[tid] = (int)atomicAdd(&gcur[tid * CURSTRIDE], (unsigned int)padded);
    }
    __syncthreads();

    // coalesced copy-out: wave w handles buckets w, w+8, ...
    int wave = tid >> 6, lane = tid & 63;
    for (int b = wave; b < NB; b += (P1B / 64)) {
        int n = lcur[b];
        int padded = (n + 3) & ~3;
        int go = gofs[b];
        long rb = (long)b * CAP;
        for (int i = lane; i < padded; i += 64) {
            // pad entries: v=0, li spread (no acc[0] hammering in phase 2)
            unsigned int val = (i < n) ? stage[b * SSTR + i]
                                       : ((unsigned int)(i & BMASK) << 21);
            int pos = go + i;
            if (pos < CAP)                       // statistical hard guard
                list[rb + pos] = val;
        }
    }
}

// ---------------- Phase 2: per-bucket-chunk LDS int accumulation ----------
__global__ __launch_bounds__(512) void ee_acc(
    const unsigned int* __restrict__ list,
    const unsigned int* __restrict__ gcur,
    int* __restrict__ partials)          // [NB*SCH][2048]
{
    __shared__ int acc[1 << BSH];
    int b = blockIdx.x / SCH;
    int s = blockIdx.x % SCH;
    int t = threadIdx.x;
#pragma unroll
    for (int r = 0; r < (1 << BSH) / 512; ++r) acc[t + r * 512] = 0;
    __syncthreads();

    int n = (int)gcur[b * CURSTRIDE];    // padded total, multiple of 4
    if (n > CAP) n = CAP;
    int nq = n >> 2;                     // uint4 count
    int per = (nq + SCH - 1) / SCH;
    int q0 = s * per;
    int q1 = q0 + per; if (q1 > nq) q1 = nq;

    const uint4* lp4 = reinterpret_cast<const uint4*>(list + (long)b * CAP);
    for (int q = q0 + t; q < q1; q += 512) {
        uint4 u4 = lp4[q];
        unsigned int us[4] = {u4.x, u4.y, u4.z, u4.w};
#pragma unroll
        for (int k = 0; k < 4; ++k) {
            unsigned int u = us[k];
            int li = (int)(u >> 21);
            int v  = ((int)(u << 11)) >> 11;   // sign-extend 21-bit payload
            atomicAdd(&acc[li], v);            // native ds_add_u32
        }
    }
    __syncthreads();

    int* pp = partials + ((long)b * SCH + s) * (1 << BSH);
#pragma unroll
    for (int r = 0; r < (1 << BSH) / 512; ++r) pp[t + r * 512] = acc[t + r * 512];
}

// ---------------- Phase 3: combine partials, apply KEHALF*Qi, add spill ----
__global__ __launch_bounds__(256) void ee_final(
    const int* __restrict__ partials,
    const float* __restrict__ Qa,
    float* __restrict__ out, int nAtoms)
{
    int q = blockIdx.x * blockDim.x + threadIdx.x;      // one int4 per thread
    int n4 = nAtoms >> 2;
    if (q >= n4) return;
    int a0 = q << 2;
    int b  = a0 >> BSH;
    int li = a0 & BMASK;
    long base = (long)(b * SCH) * (1 << BSH) + li;
    int4 s = {0, 0, 0, 0};
#pragma unroll
    for (int r = 0; r < SCH; ++r) {
        int4 p = *reinterpret_cast<const int4*>(partials + base + (long)r * (1 << BSH));
        s.x += p.x; s.y += p.y; s.z += p.z; s.w += p.w;
    }
    float4 qv = reinterpret_cast<const float4*>(Qa)[q];
    float4 sp = reinterpret_cast<const float4*>(out)[q];   // spill (or 0)
    float4 o;
    o.x = KEHALF * qv.x * ((float)s.x * VINV) + sp.x;
    o.y = KEHALF * qv.y * ((float)s.y * VINV) + sp.y;
    o.z = KEHALF * qv.z * ((float)s.z * VINV) + sp.z;
    o.w = KEHALF * qv.w * ((float)s.w * VINV) + sp.w;
    reinterpret_cast<float4*>(out)[q] = o;
}

// ---------------- Fallback: int fixed-point global atomics (R3) --------
#define FP_SCALE 4194304.0f
#define FP_INV   (1.0f / 4194304.0f)

__device__ __forceinline__ float radial_exact(float d) {
    float dsh = sqrtf(d * d + 1.0f);
    float x   = 0.5f * d;
    float sw  = (x < 1.0f) ? 1.0f - x * x * x * (x * (6.0f * x - 15.0f) + 10.0f)
                           : 0.0f;
    float Eo = 1.0f / d   + d   * 0.01f - 0.2f;
    float Es = 1.0f / dsh + dsh * 0.01f - 0.2f;
    return sw * Es + (1.0f - sw) * Eo;
}

__global__ __launch_bounds__(256) void ee_pair_fix(
    const float* __restrict__ Dij,
    const float* __restrict__ Qa,
    const int*   __restrict__ idx_i,
    const int*   __restrict__ idx_j,
    int*         __restrict__ acc,
    int P)
{
    long base = ((long)blockIdx.x * blockDim.x + threadIdx.x) * 4;
    if (base >= P) return;
    float4 d4 = *reinterpret_cast<const float4*>(Dij + base);
    int4   i4 = *reinterpret_cast<const int4*>(idx_i + base);
    int4   j4 = *reinterpret_cast<const int4*>(idx_j + base);
    float D[4]  = {d4.x, d4.y, d4.z, d4.w};
    int   ii[4] = {i4.x, i4.y, i4.z, i4.w};
    int   jj[4] = {j4.x, j4.y, j4.z, j4.w};
#pragma unroll
    for (int k = 0; k < 4; ++k) {
        float d = D[k];
        if (d > 10.0f) continue;
        float e = KEHALF * Qa[ii[k]] * Qa[jj[k]] * radial_exact(d);
        atomicAdd(acc + ii[k], __float2int_rn(e * FP_SCALE));
    }
}

__global__ __launch_bounds__(256) void ee_convert(
    const int* __restrict__ acc, float* __restrict__ out, int nAtoms)
{
    int n4 = nAtoms >> 2;
    int q = blockIdx.x * blockDim.x + threadIdx.x;
    if (q >= n4) return;
    int4 a = reinterpret_cast<const int4*>(acc)[q];
    float4 o;
    o.x = (float)a.x * FP_INV;
    o.y = (float)a.y * FP_INV;
    o.z = (float)a.z * FP_INV;
    o.w = (float)a.w * FP_INV;
    reinterpret_cast<float4*>(out)[q] = o;
}

__global__ __launch_bounds__(256) void ee_pair_direct(
    const float* __restrict__ Dij,
    const float* __restrict__ Qa,
    const int*   __restrict__ idx_i,
    const int*   __restrict__ idx_j,
    float*       __restrict__ out,
    int P)
{
    long t = (long)blockIdx.x * blockDim.x + threadIdx.x;
    if (t >= P) return;
    float d = Dij[t];
    if (d > 10.0f) return;
    atomicAdd(out + idx_i[t], KEHALF * Qa[idx_i[t]] * Qa[idx_j[t]] * radial_exact(d));
}

extern "C" void kernel_launch(void* const* d_in, const int* in_sizes, int n_in,
                              void* d_out, int out_size, void* d_ws, size_t ws_size,
                              hipStream_t stream) {
    const float* Dij   = (const float*)d_in[0];
    const float* Qa    = (const float*)d_in[1];
    const int*   idx_i = (const int*)d_in[2];
    const int*   idx_j = (const int*)d_in[3];
    float*       out   = (float*)d_out;

    int P      = in_sizes[0];
    int nAtoms = in_sizes[1];

    size_t listBytes = (size_t)NB * CAP * sizeof(unsigned int);          // 62 MiB
    size_t partBytes = (size_t)NB * SCH * (1 << BSH) * sizeof(int);      // 2 MiB
    size_t curBytes  = (size_t)NB * CURSTRIDE * sizeof(unsigned int);    // 8 KiB

    if (ws_size >= listBytes + partBytes + curBytes &&
        nAtoms == NB * (1 << BSH) && (P % P1PAIRS) == 0) {
        unsigned int* list = (unsigned int*)d_ws;
        int*          part = (int*)((char*)d_ws + listBytes);
        unsigned int* gcur = (unsigned int*)((char*)d_ws + listBytes + partBytes);
        hipMemsetAsync(gcur, 0, curBytes, stream);
        hipMemsetAsync(out, 0, (size_t)out_size * sizeof(float), stream); // spill base
        int grid1 = P / P1PAIRS;                                          // 2048
        ee_bin<<<grid1, P1B, 0, stream>>>(Dij, Qa, idx_i, idx_j, list, gcur, out);
        ee_acc<<<NB * SCH, 512, 0, stream>>>(list, gcur, part);
        ee_final<<<(nAtoms / 4 + 255) / 256, 256, 0, stream>>>(part, Qa, out, nAtoms);
    } else if (ws_size >= (size_t)nAtoms * sizeof(int) &&
               (nAtoms & 3) == 0 && (P & 3) == 0) {
        int* acc = (int*)d_ws;
        hipMemsetAsync(acc, 0, (size_t)nAtoms * sizeof(int), stream);
        int grid = (P / 4 + 255) / 256;
        ee_pair_fix<<<grid, 256, 0, stream>>>(Dij, Qa, idx_i, idx_j, acc, P);
        ee_convert<<<(nAtoms / 4 + 255) / 256, 256, 0, stream>>>(acc, out, nAtoms);
    } else {
        hipMemsetAsync(out, 0, (size_t)out_size * sizeof(float), stream);
        int grid = (P + 255) / 256;
        ee_pair_direct<<<grid, 256, 0, stream>>>(Dij, Qa, idx_i, idx_j, out, P);
    }
}